// Round 9
// baseline (210.069 us; speedup 1.0000x reference)
//
#include <hip/hip_runtime.h>
#include <hip/hip_bf16.h>

#define N_NODES 50000
#define N_EDGES 800000
#define F_IN    128
#define F_HID   128
#define F_OUT   40
#define F_OUT_P 64                            // h2b padded stride (1 cache line)
#define N_TILES (N_NODES / 16)                // 3125 (exact)

#define NBIN      98                          // bins of 512 nodes (dst >> 9)
#define BIN_SHIFT 9
#define EPB       1024                        // edges per bin block
#define CAP       32                          // LDS slots per bin
#define GBIN_CAP  9216                        // global slots per bin

#define CVT_BLOCKS ((F_IN * F_HID + F_OUT_P * F_HID) / 256)   // 96
#define BIN_BLOCKS ((N_EDGES + EPB - 1) / EPB)           // 782
#define G1_BLOCKS  ((N_TILES + 3) / 4)                   // 782

typedef __attribute__((ext_vector_type(8))) short bf16x8;   // 8 bf16 = 4 VGPRs
typedef __attribute__((ext_vector_type(4))) float f32x4;

__device__ __forceinline__ float2 unpack_bf2(unsigned u) {
    float2 r;
    r.x = __uint_as_float(u << 16);
    r.y = __uint_as_float(u & 0xffff0000u);
    return r;
}
__device__ __forceinline__ unsigned pack_bf2(float x, float y) {
    union { unsigned u; __hip_bfloat16 h[2]; } cv;
    cv.h[0] = __float2bfloat16(x);
    cv.h[1] = __float2bfloat16(y);
    return cv.u;
}
__device__ __forceinline__ short bfraw(float v) {
    __hip_bfloat16 h = __float2bfloat16(v);
    return *(short*)&h;
}
__device__ __forceinline__ float bf16u_to_f32(unsigned short us) {
    return __uint_as_float(((unsigned)us) << 16);
}

__device__ __forceinline__ int ld_src(const unsigned int* w, int is64, int e) {
    return is64 ? (int)w[2 * e] : (int)w[e];
}
__device__ __forceinline__ int ld_dst(const unsigned int* w, int is64, int e) {
    return is64 ? (int)w[2 * (N_EDGES + e)] : (int)w[N_EDGES + e];
}

// ---- 1. init: blocks 0..95 convert W1/W2 to transposed bf16 (W2 padded to 64
//         rows); block 96 sniffs index width and zeroes gcnt.
__global__ void k_init(const unsigned int* __restrict__ ew,
                       const float* __restrict__ W1, const float* __restrict__ W2,
                       __hip_bfloat16* __restrict__ w1t, __hip_bfloat16* __restrict__ w2t,
                       int* __restrict__ flag, int* __restrict__ gcnt) {
    int b = blockIdx.x, t = threadIdx.x;
    if (b < CVT_BLOCKS) {
        int idx = b * 256 + t;
        if (idx < F_IN * F_HID) {
            int n = idx >> 7, k = idx & 127;
            w1t[idx] = __float2bfloat16(W1[k * F_HID + n]);
        } else {
            int j = idx - F_IN * F_HID;          // 0 .. 8191
            int n = j >> 7, k = j & 127;         // n: 0 .. 63
            w2t[j] = __float2bfloat16(n < F_OUT ? W2[k * F_OUT + n] : 0.f);
        }
        return;
    }
    __shared__ int nz;
    if (t == 0) nz = 0;
    __syncthreads();
    int local = 0;
    for (int i = t; i < 4096; i += 256)
        if (ew[2 * i + 1] != 0u) local = 1;
    if (local) atomicOr(&nz, 1);
    if (t < NBIN) gcnt[t] = 0;
    __syncthreads();
    if (t == 0) flag[0] = (nz == 0) ? 1 : 0;     // 1 => int64 layout
}

// ---- 2. merged: blocks [0,782) bin edges (ILP fast path); blocks [782,1564)
//         MFMA gemm1 (row-major h1b).
__global__ void k_bing1(const unsigned int* __restrict__ ew, const int* __restrict__ flag,
                        int* __restrict__ gcnt, unsigned* __restrict__ gbin,
                        const float* __restrict__ x, const __hip_bfloat16* __restrict__ w1t,
                        __hip_bfloat16* __restrict__ h1b) {
    __shared__ unsigned buf[NBIN][CAP];        // 12.5 KB (unused by gemm blocks)
    __shared__ int cnt[NBIN];
    __shared__ int base[NBIN];
    int t = threadIdx.x;
    if (blockIdx.x < BIN_BLOCKS) {
        for (int i = t; i < NBIN; i += 256) cnt[i] = 0;
        __syncthreads();
        int is64 = flag[0];
        int e0 = blockIdx.x * EPB;
        int n = min(EPB, N_EDGES - e0);
        if (n == EPB) {
            // fast path: 4 edges/thread, loads batched ahead of the atomic chain
            int s[4], d[4];
#pragma unroll
            for (int j = 0; j < 4; j++) {
                int e = e0 + t + j * 256;
                s[j] = ld_src(ew, is64, e);
                d[j] = ld_dst(ew, is64, e);
            }
#pragma unroll
            for (int j = 0; j < 4; j++) {
                unsigned rec = (unsigned)s[j] | ((unsigned)d[j] << 16);
                int b = d[j] >> BIN_SHIFT;
                int c = atomicAdd(&cnt[b], 1);
                if (c < CAP) buf[b][c] = rec;
                else {
                    int g = atomicAdd(&gcnt[b], 1);
                    gbin[(size_t)b * GBIN_CAP + g] = rec;
                }
            }
        } else {
            for (int i = t; i < n; i += 256) {
                int e = e0 + i;
                int s = ld_src(ew, is64, e), d = ld_dst(ew, is64, e);
                unsigned rec = (unsigned)s | ((unsigned)d << 16);
                int b = d >> BIN_SHIFT;
                int c = atomicAdd(&cnt[b], 1);
                if (c < CAP) buf[b][c] = rec;
                else {
                    int g = atomicAdd(&gcnt[b], 1);
                    gbin[(size_t)b * GBIN_CAP + g] = rec;
                }
            }
        }
        __syncthreads();
        if (t < NBIN) {
            int m = min(cnt[t], CAP);
            base[t] = atomicAdd(&gcnt[t], m);
            cnt[t] = m;
        }
        __syncthreads();
        int wave = t >> 6, lane = t & 63;
        for (int b = wave; b < NBIN; b += 4) {
            int m = cnt[b], bs = base[b];
            for (int i = lane; i < m; i += 64)
                gbin[(size_t)b * GBIN_CAP + bs + i] = buf[b][i];
        }
        return;
    }
    // ---- gemm1 part
    int wave = t >> 6, lane = t & 63;
    int tile = (blockIdx.x - BIN_BLOCKS) * 4 + wave;
    if (tile >= N_TILES) return;
    int node0 = tile * 16;
    int m = lane & 15, q = lane >> 4;
    bf16x8 A[4];
    const float* arow = x + (size_t)(node0 + m) * F_IN + q * 8;
#pragma unroll
    for (int kt = 0; kt < 4; kt++) {
        float4 f0 = *(const float4*)(arow + kt * 32);
        float4 f1 = *(const float4*)(arow + kt * 32 + 4);
        bf16x8 a;
        a[0] = bfraw(f0.x); a[1] = bfraw(f0.y); a[2] = bfraw(f0.z); a[3] = bfraw(f0.w);
        a[4] = bfraw(f1.x); a[5] = bfraw(f1.y); a[6] = bfraw(f1.z); a[7] = bfraw(f1.w);
        A[kt] = a;
    }
#pragma unroll
    for (int c = 0; c < 8; c++) {
        f32x4 acc = {0.f, 0.f, 0.f, 0.f};
        const __hip_bfloat16* brow = w1t + (size_t)(c * 16 + m) * F_IN + q * 8;
#pragma unroll
        for (int kt = 0; kt < 4; kt++) {
            bf16x8 B = *(const bf16x8*)(brow + kt * 32);
            acc = __builtin_amdgcn_mfma_f32_16x16x32_bf16(A[kt], B, acc, 0, 0, 0);
        }
#pragma unroll
        for (int r = 0; r < 4; r++)
            h1b[(size_t)(node0 + q * 4 + r) * F_HID + c * 16 + m] = __float2bfloat16(acc[r]);
    }
}

// ---- 3. merged passB: histogram -> scan -> scatter, one 98-block kernel.
//         Records now carry SRC ONLY; norm weights are computed on the fly in
//         the agg kernels from dinv (removes the passB1/passB2 split, one
//         fewer launch, no f16 weight rounding).
__global__ void k_passB(const int* __restrict__ gcnt, const unsigned* __restrict__ gbin,
                        int* __restrict__ rowptr, float* __restrict__ dinv,
                        unsigned* __restrict__ srcw) {
    __shared__ int c[512];
    __shared__ int s2[256];
    __shared__ int gall[NBIN];
    __shared__ int bbase;
    __shared__ int pos[512];
    int t = threadIdx.x;
    int b = blockIdx.x;
    c[t] = 0; c[t + 256] = 0;
    if (t < NBIN) gall[t] = gcnt[t];
    __syncthreads();
    if (t == 0) {
        int s = 0;
        for (int i = 0; i < b; i++) s += gall[i];
        bbase = s;
    }
    int n = gall[b];
    const unsigned* rec = gbin + (size_t)b * GBIN_CAP;
    int base512 = b << BIN_SHIFT;
    for (int i = t; i < n; i += 256)
        atomicAdd(&c[(int)(rec[i] >> 16) - base512], 1);
    __syncthreads();
    int a0 = c[2 * t], a1 = c[2 * t + 1];
    s2[t] = a0 + a1;
    __syncthreads();
    for (int off = 1; off < 256; off <<= 1) {
        int u = (t >= off) ? s2[t - off] : 0;
        __syncthreads();
        s2[t] += u;
        __syncthreads();
    }
    int ebase = bbase + s2[t] - a0 - a1;
    int i0 = base512 + 2 * t, i1 = i0 + 1;
    if (i0 < N_NODES) { rowptr[i0] = ebase;      dinv[i0] = rsqrtf((float)a0 + 1.f); }
    if (i1 < N_NODES) { rowptr[i1] = ebase + a0; dinv[i1] = rsqrtf((float)a1 + 1.f); }
    pos[2 * t]     = ebase;
    pos[2 * t + 1] = ebase + a0;
    if (b == 0 && t == 0) rowptr[N_NODES] = N_EDGES;
    __syncthreads();
    for (int i = t; i < n; i += 256) {
        unsigned r = rec[i];
        int dl = (int)(r >> 16) - base512;
        int slot = atomicAdd(&pos[dl], 1);
        srcw[slot] = r & 0xFFFFu;               // src index only
    }
}

// ---- 4. fused layer-1 aggregate + self-loop + bias + relu + gemm2 for a
//         16-node tile.  Weight = dinv[src]*dinv[dst], dinv[src] via scalar
//         load (uniform address chain: s_load srcw -> s_load dinv).
__global__ void k_agg1g2(const int* __restrict__ rowptr, const unsigned* __restrict__ srcw,
                         const float* __restrict__ dinv, const __hip_bfloat16* __restrict__ h1b,
                         const float* __restrict__ b1, const __hip_bfloat16* __restrict__ w2t,
                         __hip_bfloat16* __restrict__ h2b) {
    __shared__ __align__(16) short h1r[16][136];   // +8 bf16 pad
    int t = threadIdx.x, wave = t >> 6, lane = t & 63;
    int node0 = blockIdx.x * 16;
    const unsigned* h1u = (const unsigned*)h1b;
#pragma unroll
    for (int i = 0; i < 4; i++) {
        int row = wave * 4 + i;
        int node = node0 + row;
        float di = dinv[node];
        int beg = __builtin_amdgcn_readfirstlane(rowptr[node]);
        int end = __builtin_amdgcn_readfirstlane(rowptr[node + 1]);
        float2 acc = unpack_bf2(h1u[(size_t)node * 64 + lane]);
        float w0 = di * di;
        acc.x *= w0; acc.y *= w0;
        int e = beg;
        for (; e + 7 < end; e += 8) {
            unsigned p[8];
#pragma unroll
            for (int j = 0; j < 8; j++) p[j] = srcw[e + j];       // uniform -> s_load
            float ws[8];
#pragma unroll
            for (int j = 0; j < 8; j++) ws[j] = dinv[p[j]];       // uniform -> s_load
            unsigned u[8];
#pragma unroll
            for (int j = 0; j < 8; j++)
                u[j] = h1u[(size_t)p[j] * 64 + lane];
#pragma unroll
            for (int j = 0; j < 8; j++) {
                float w = ws[j] * di;
                float2 v = unpack_bf2(u[j]);
                acc.x += v.x * w;
                acc.y += v.y * w;
            }
        }
        for (; e < end; e++) {
            unsigned p = srcw[e];
            float w = dinv[p] * di;
            float2 v = unpack_bf2(h1u[(size_t)p * 64 + lane]);
            acc.x += v.x * w;
            acc.y += v.y * w;
        }
        float2 bb = ((const float2*)b1)[lane];
        acc.x = fmaxf(acc.x + bb.x, 0.f);
        acc.y = fmaxf(acc.y + bb.y, 0.f);
        ((unsigned*)&h1r[row][0])[lane] = pack_bf2(acc.x, acc.y);
    }
    __syncthreads();
    // 4 waves x 1 column-tile of 16 = 64 padded output columns
    {
        int m = lane & 15, q = lane >> 4;
        bf16x8 A[4];
#pragma unroll
        for (int kt = 0; kt < 4; kt++)
            A[kt] = *(const bf16x8*)(&h1r[m][q * 8 + kt * 32]);
        int c = wave;
        f32x4 acc = {0.f, 0.f, 0.f, 0.f};
        const __hip_bfloat16* brow = w2t + (size_t)(c * 16 + m) * F_HID + q * 8;
#pragma unroll
        for (int kt = 0; kt < 4; kt++) {
            bf16x8 B = *(const bf16x8*)(brow + kt * 32);
            acc = __builtin_amdgcn_mfma_f32_16x16x32_bf16(A[kt], B, acc, 0, 0, 0);
        }
        int col = c * 16 + m;
#pragma unroll
        for (int r = 0; r < 4; r++)
            h2b[(size_t)(node0 + q * 4 + r) * F_OUT_P + col] = __float2bfloat16(acc[r]);
    }
}

// ---- 5. fused layer-2 aggregate + self-loop + bias + log_softmax.
//         h2b rows are 64 bf16 = one 128B line; weights on the fly from dinv.
__global__ void k_agg2f(const int* __restrict__ rowptr, const unsigned* __restrict__ srcw,
                        const float* __restrict__ dinv,
                        const unsigned short* __restrict__ h2b,
                        const float* __restrict__ b2, float* __restrict__ out) {
    int wave = threadIdx.x >> 6, lane = threadIdx.x & 63;
    int node = blockIdx.x * 4 + wave;
    float di = dinv[node];
    int beg = __builtin_amdgcn_readfirstlane(rowptr[node]);
    int end = __builtin_amdgcn_readfirstlane(rowptr[node + 1]);
    float acc = bf16u_to_f32(h2b[(size_t)node * F_OUT_P + lane]) * di * di;
    int e = beg;
    for (; e + 7 < end; e += 8) {
        unsigned p[8];
#pragma unroll
        for (int j = 0; j < 8; j++) p[j] = srcw[e + j];          // uniform -> s_load
        float ws[8];
#pragma unroll
        for (int j = 0; j < 8; j++) ws[j] = dinv[p[j]];          // uniform -> s_load
        float v[8];
#pragma unroll
        for (int j = 0; j < 8; j++)
            v[j] = bf16u_to_f32(h2b[(size_t)p[j] * F_OUT_P + lane]);
#pragma unroll
        for (int j = 0; j < 8; j++)
            acc += v[j] * (ws[j] * di);
    }
    for (; e < end; e++) {
        unsigned p = srcw[e];
        acc += bf16u_to_f32(h2b[(size_t)p * F_OUT_P + lane]) * (dinv[p] * di);
    }
    float v = (lane < F_OUT) ? acc + b2[lane] : -INFINITY;
    float m = v;
    for (int off = 32; off; off >>= 1) m = fmaxf(m, __shfl_xor(m, off));
    float ex = (lane < F_OUT) ? __expf(v - m) : 0.f;
    float ssum = ex;
    for (int off = 32; off; off >>= 1) ssum += __shfl_xor(ssum, off);
    float ls = __logf(ssum);
    if (lane < F_OUT)
        out[(size_t)node * F_OUT + lane] = v - m - ls;
}

extern "C" void kernel_launch(void* const* d_in, const int* in_sizes, int n_in,
                              void* d_out, int out_size, void* d_ws, size_t ws_size,
                              hipStream_t stream) {
    const float* x  = (const float*)d_in[0];
    const float* W1 = (const float*)d_in[1];
    const float* b1 = (const float*)d_in[2];
    const float* W2 = (const float*)d_in[3];
    const float* b2 = (const float*)d_in[4];
    const unsigned int* ew = (const unsigned int*)d_in[5];
    float* out = (float*)d_out;

    // workspace (~27 MB)
    char* ws = (char*)d_ws;
    int*   flag     = (int*)ws;   ws += 256;
    int*   gcnt     = (int*)ws;   ws += 512;
    float* dinv     = (float*)ws; ws += ((N_NODES * 4 + 255) / 256) * 256;
    int*   rowptr   = (int*)ws;   ws += (((N_NODES + 1) * 4 + 255) / 256) * 256;
    unsigned* gbin  = (unsigned*)ws; ws += (size_t)NBIN * GBIN_CAP * 4;   // 3.6 MB
    unsigned* srcw  = (unsigned*)ws; ws += (size_t)N_EDGES * 4;           // 3.2 MB
    __hip_bfloat16* w1t  = (__hip_bfloat16*)ws; ws += F_IN * F_HID * 2;
    __hip_bfloat16* w2t  = (__hip_bfloat16*)ws; ws += F_OUT_P * F_HID * 2;
    __hip_bfloat16* h1b  = (__hip_bfloat16*)ws; ws += (size_t)N_NODES * F_HID * 2;  // row-major
    __hip_bfloat16* h2b  = (__hip_bfloat16*)ws; ws += (size_t)N_NODES * F_OUT_P * 2; // 6.4 MB

    k_init   <<<CVT_BLOCKS + 1, 256, 0, stream>>>(ew, W1, W2, w1t, w2t, flag, gcnt);
    k_bing1  <<<BIN_BLOCKS + G1_BLOCKS, 256, 0, stream>>>(ew, flag, gcnt, gbin, x, w1t, h1b);
    k_passB  <<<NBIN, 256, 0, stream>>>(gcnt, gbin, rowptr, dinv, srcw);
    k_agg1g2 <<<N_NODES / 16, 256, 0, stream>>>(rowptr, srcw, dinv, h1b, b1, w2t, h2b);
    k_agg2f  <<<N_NODES / 4, 256, 0, stream>>>(rowptr, srcw, dinv,
                                               (const unsigned short*)h2b, b2, out);
}

// Round 10
// 208.741 us; speedup vs baseline: 1.0064x; 1.0064x over previous
//
#include <hip/hip_runtime.h>
#include <hip/hip_bf16.h>

#define N_NODES 50000
#define N_EDGES 800000
#define F_IN    128
#define F_HID   128
#define F_OUT   40
#define F_OUT_P 64                            // h2b padded stride (1 cache line)
#define N_TILES (N_NODES / 16)                // 3125 (exact)

#define NBIN      98                          // bins of 512 nodes (dst >> 9)
#define BIN_SHIFT 9
#define EPB       1024                        // edges per bin block
#define CAP       32                          // LDS slots per bin
#define GBIN_CAP  9216                        // global slots per bin

#define CVT_BLOCKS ((F_IN * F_HID + F_OUT_P * F_HID) / 256)   // 96
#define BIN_BLOCKS ((N_EDGES + EPB - 1) / EPB)           // 782
#define G1_BLOCKS  ((N_TILES + 3) / 4)                   // 782

typedef __attribute__((ext_vector_type(8))) short bf16x8;   // 8 bf16 = 4 VGPRs
typedef __attribute__((ext_vector_type(4))) float f32x4;

__device__ __forceinline__ float2 unpack_bf2(unsigned u) {
    float2 r;
    r.x = __uint_as_float(u << 16);
    r.y = __uint_as_float(u & 0xffff0000u);
    return r;
}
__device__ __forceinline__ unsigned pack_bf2(float x, float y) {
    union { unsigned u; __hip_bfloat16 h[2]; } cv;
    cv.h[0] = __float2bfloat16(x);
    cv.h[1] = __float2bfloat16(y);
    return cv.u;
}
__device__ __forceinline__ short bfraw(float v) {
    __hip_bfloat16 h = __float2bfloat16(v);
    return *(short*)&h;
}
__device__ __forceinline__ float bf16u_to_f32(unsigned short us) {
    return __uint_as_float(((unsigned)us) << 16);
}
__device__ __forceinline__ unsigned f32_to_h16(float v) {
    _Float16 h = (_Float16)v;
    return (unsigned)*(unsigned short*)&h;
}
__device__ __forceinline__ float h16_to_f32(unsigned bits) {
    unsigned short us = (unsigned short)bits;
    _Float16 h = *(_Float16*)&us;
    return (float)h;
}

__device__ __forceinline__ int ld_src(const unsigned int* w, int is64, int e) {
    return is64 ? (int)w[2 * e] : (int)w[e];
}
__device__ __forceinline__ int ld_dst(const unsigned int* w, int is64, int e) {
    return is64 ? (int)w[2 * (N_EDGES + e)] : (int)w[N_EDGES + e];
}

// ---- 1. init: blocks 0..95 convert W1/W2 to transposed bf16 (W2 padded to 64
//         rows); block 96 sniffs index width and zeroes gcnt.
__global__ void k_init(const unsigned int* __restrict__ ew,
                       const float* __restrict__ W1, const float* __restrict__ W2,
                       __hip_bfloat16* __restrict__ w1t, __hip_bfloat16* __restrict__ w2t,
                       int* __restrict__ flag, int* __restrict__ gcnt) {
    int b = blockIdx.x, t = threadIdx.x;
    if (b < CVT_BLOCKS) {
        int idx = b * 256 + t;
        if (idx < F_IN * F_HID) {
            int n = idx >> 7, k = idx & 127;
            w1t[idx] = __float2bfloat16(W1[k * F_HID + n]);
        } else {
            int j = idx - F_IN * F_HID;          // 0 .. 8191
            int n = j >> 7, k = j & 127;         // n: 0 .. 63
            w2t[j] = __float2bfloat16(n < F_OUT ? W2[k * F_OUT + n] : 0.f);
        }
        return;
    }
    __shared__ int nz;
    if (t == 0) nz = 0;
    __syncthreads();
    int local = 0;
    for (int i = t; i < 4096; i += 256)
        if (ew[2 * i + 1] != 0u) local = 1;
    if (local) atomicOr(&nz, 1);
    if (t < NBIN) gcnt[t] = 0;
    __syncthreads();
    if (t == 0) flag[0] = (nz == 0) ? 1 : 0;     // 1 => int64 layout
}

// ---- 2. merged: blocks [0,782) bin edges (ILP fast path); blocks [782,1564)
//         MFMA gemm1 (row-major h1b).
__global__ void k_bing1(const unsigned int* __restrict__ ew, const int* __restrict__ flag,
                        int* __restrict__ gcnt, unsigned* __restrict__ gbin,
                        const float* __restrict__ x, const __hip_bfloat16* __restrict__ w1t,
                        __hip_bfloat16* __restrict__ h1b) {
    __shared__ unsigned buf[NBIN][CAP];        // 12.5 KB (unused by gemm blocks)
    __shared__ int cnt[NBIN];
    __shared__ int base[NBIN];
    int t = threadIdx.x;
    if (blockIdx.x < BIN_BLOCKS) {
        for (int i = t; i < NBIN; i += 256) cnt[i] = 0;
        __syncthreads();
        int is64 = flag[0];
        int e0 = blockIdx.x * EPB;
        int n = min(EPB, N_EDGES - e0);
        if (n == EPB) {
            // fast path: 4 edges/thread, loads batched ahead of the atomic chain
            int s[4], d[4];
#pragma unroll
            for (int j = 0; j < 4; j++) {
                int e = e0 + t + j * 256;
                s[j] = ld_src(ew, is64, e);
                d[j] = ld_dst(ew, is64, e);
            }
#pragma unroll
            for (int j = 0; j < 4; j++) {
                unsigned rec = (unsigned)s[j] | ((unsigned)d[j] << 16);
                int b = d[j] >> BIN_SHIFT;
                int c = atomicAdd(&cnt[b], 1);
                if (c < CAP) buf[b][c] = rec;
                else {
                    int g = atomicAdd(&gcnt[b], 1);
                    gbin[(size_t)b * GBIN_CAP + g] = rec;
                }
            }
        } else {
            for (int i = t; i < n; i += 256) {
                int e = e0 + i;
                int s = ld_src(ew, is64, e), d = ld_dst(ew, is64, e);
                unsigned rec = (unsigned)s | ((unsigned)d << 16);
                int b = d >> BIN_SHIFT;
                int c = atomicAdd(&cnt[b], 1);
                if (c < CAP) buf[b][c] = rec;
                else {
                    int g = atomicAdd(&gcnt[b], 1);
                    gbin[(size_t)b * GBIN_CAP + g] = rec;
                }
            }
        }
        __syncthreads();
        if (t < NBIN) {
            int m = min(cnt[t], CAP);
            base[t] = atomicAdd(&gcnt[t], m);
            cnt[t] = m;
        }
        __syncthreads();
        int wave = t >> 6, lane = t & 63;
        for (int b = wave; b < NBIN; b += 4) {
            int m = cnt[b], bs = base[b];
            for (int i = lane; i < m; i += 64)
                gbin[(size_t)b * GBIN_CAP + bs + i] = buf[b][i];
        }
        return;
    }
    // ---- gemm1 part
    int wave = t >> 6, lane = t & 63;
    int tile = (blockIdx.x - BIN_BLOCKS) * 4 + wave;
    if (tile >= N_TILES) return;
    int node0 = tile * 16;
    int m = lane & 15, q = lane >> 4;
    bf16x8 A[4];
    const float* arow = x + (size_t)(node0 + m) * F_IN + q * 8;
#pragma unroll
    for (int kt = 0; kt < 4; kt++) {
        float4 f0 = *(const float4*)(arow + kt * 32);
        float4 f1 = *(const float4*)(arow + kt * 32 + 4);
        bf16x8 a;
        a[0] = bfraw(f0.x); a[1] = bfraw(f0.y); a[2] = bfraw(f0.z); a[3] = bfraw(f0.w);
        a[4] = bfraw(f1.x); a[5] = bfraw(f1.y); a[6] = bfraw(f1.z); a[7] = bfraw(f1.w);
        A[kt] = a;
    }
#pragma unroll
    for (int c = 0; c < 8; c++) {
        f32x4 acc = {0.f, 0.f, 0.f, 0.f};
        const __hip_bfloat16* brow = w1t + (size_t)(c * 16 + m) * F_IN + q * 8;
#pragma unroll
        for (int kt = 0; kt < 4; kt++) {
            bf16x8 B = *(const bf16x8*)(brow + kt * 32);
            acc = __builtin_amdgcn_mfma_f32_16x16x32_bf16(A[kt], B, acc, 0, 0, 0);
        }
#pragma unroll
        for (int r = 0; r < 4; r++)
            h1b[(size_t)(node0 + q * 4 + r) * F_HID + c * 16 + m] = __float2bfloat16(acc[r]);
    }
}

// ---- 3. passB1: per-bin node histogram + scan -> rowptr, dinv.
__global__ void k_passB1(const int* __restrict__ gcnt, const unsigned* __restrict__ gbin,
                         int* __restrict__ rowptr, float* __restrict__ dinv) {
    __shared__ int c[512];
    __shared__ int s2[256];
    __shared__ int gall[NBIN];
    __shared__ int bbase;
    int t = threadIdx.x;
    int b = blockIdx.x;
    c[t] = 0; c[t + 256] = 0;
    if (t < NBIN) gall[t] = gcnt[t];
    __syncthreads();
    if (t == 0) {
        int s = 0;
        for (int i = 0; i < b; i++) s += gall[i];
        bbase = s;
    }
    int n = gall[b];
    const unsigned* rec = gbin + (size_t)b * GBIN_CAP;
    int base512 = b << BIN_SHIFT;
    for (int i = t; i < n; i += 256)
        atomicAdd(&c[(int)(rec[i] >> 16) - base512], 1);
    __syncthreads();
    int a0 = c[2 * t], a1 = c[2 * t + 1];
    s2[t] = a0 + a1;
    __syncthreads();
    for (int off = 1; off < 256; off <<= 1) {
        int u = (t >= off) ? s2[t - off] : 0;
        __syncthreads();
        s2[t] += u;
        __syncthreads();
    }
    int ebase = bbase + s2[t] - a0 - a1;
    int i0 = base512 + 2 * t, i1 = i0 + 1;
    if (i0 < N_NODES) { rowptr[i0] = ebase;      dinv[i0] = rsqrtf((float)a0 + 1.f); }
    if (i1 < N_NODES) { rowptr[i1] = ebase + a0; dinv[i1] = rsqrtf((float)a1 + 1.f); }
    if (b == 0 && t == 0) rowptr[N_NODES] = N_EDGES;
}

// ---- 4. passB2: scatter bin records to final CSR slots (f16 weight packed).
__global__ void k_passB2(const int* __restrict__ gcnt, const unsigned* __restrict__ gbin,
                         const int* __restrict__ rowptr, const float* __restrict__ dinv,
                         unsigned* __restrict__ srcw) {
    __shared__ int pos[512];
    __shared__ float dloc[512];
    int t = threadIdx.x;
    int b = blockIdx.x;
    int base512 = b << BIN_SHIFT;
#pragma unroll
    for (int k = 0; k < 2; k++) {
        int j = t + k * 256;
        int i = base512 + j;
        pos[j]  = (i < N_NODES) ? rowptr[i] : 0;
        dloc[j] = (i < N_NODES) ? dinv[i] : 0.f;
    }
    __syncthreads();
    int n = gcnt[b];
    const unsigned* rec = gbin + (size_t)b * GBIN_CAP;
    for (int i = t; i < n; i += 256) {
        unsigned r = rec[i];
        int s  = (int)(r & 0xFFFFu);
        int dl = (int)(r >> 16) - base512;
        int slot = atomicAdd(&pos[dl], 1);
        float norm = dinv[s] * dloc[dl];
        srcw[slot] = (unsigned)s | (f32_to_h16(norm) << 16);
    }
}

// ---- 5. fused layer-1 aggregate + self-loop + bias + relu + gemm2 for a
//         16-node tile.  Edge loop SOFTWARE-PIPELINED: batch k+1's records +
//         row gathers issue before batch k's FMAs consume (16 gathers in
//         flight per wave instead of 8).
__global__ void k_agg1g2(const int* __restrict__ rowptr, const unsigned* __restrict__ srcw,
                         const float* __restrict__ dinv, const __hip_bfloat16* __restrict__ h1b,
                         const float* __restrict__ b1, const __hip_bfloat16* __restrict__ w2t,
                         __hip_bfloat16* __restrict__ h2b) {
    __shared__ __align__(16) short h1r[16][136];   // +8 bf16 pad
    int t = threadIdx.x, wave = t >> 6, lane = t & 63;
    int node0 = blockIdx.x * 16;
    const unsigned* h1u = (const unsigned*)h1b;
#pragma unroll
    for (int i = 0; i < 4; i++) {
        int row = wave * 4 + i;
        int node = node0 + row;
        float di = dinv[node];
        int beg = __builtin_amdgcn_readfirstlane(rowptr[node]);
        int end = __builtin_amdgcn_readfirstlane(rowptr[node + 1]);
        float2 acc = unpack_bf2(h1u[(size_t)node * 64 + lane]);
        float w0 = di * di;
        acc.x *= w0; acc.y *= w0;
        int e = beg;
        int nfull = (end - e) >> 3;
        if (nfull > 0) {
            unsigned pc[8], uc[8];
#pragma unroll
            for (int j = 0; j < 8; j++) pc[j] = srcw[e + j];          // s_load x8
#pragma unroll
            for (int j = 0; j < 8; j++)
                uc[j] = h1u[(size_t)(pc[j] & 0xFFFFu) * 64 + lane];   // gathers
            e += 8;
            for (int k = 1; k < nfull; k++) {
                unsigned pn[8], un[8];
#pragma unroll
                for (int j = 0; j < 8; j++) pn[j] = srcw[e + j];      // next batch issues
#pragma unroll
                for (int j = 0; j < 8; j++)
                    un[j] = h1u[(size_t)(pn[j] & 0xFFFFu) * 64 + lane];
                e += 8;
#pragma unroll
                for (int j = 0; j < 8; j++) {                         // consume current
                    float w = h16_to_f32(pc[j] >> 16);
                    float2 v = unpack_bf2(uc[j]);
                    acc.x += v.x * w;
                    acc.y += v.y * w;
                }
#pragma unroll
                for (int j = 0; j < 8; j++) { pc[j] = pn[j]; uc[j] = un[j]; }
            }
#pragma unroll
            for (int j = 0; j < 8; j++) {                             // drain
                float w = h16_to_f32(pc[j] >> 16);
                float2 v = unpack_bf2(uc[j]);
                acc.x += v.x * w;
                acc.y += v.y * w;
            }
        }
        for (; e < end; e++) {
            unsigned p = srcw[e];
            float w = h16_to_f32(p >> 16);
            float2 v = unpack_bf2(h1u[(size_t)(p & 0xFFFFu) * 64 + lane]);
            acc.x += v.x * w;
            acc.y += v.y * w;
        }
        float2 bb = ((const float2*)b1)[lane];
        acc.x = fmaxf(acc.x + bb.x, 0.f);
        acc.y = fmaxf(acc.y + bb.y, 0.f);
        ((unsigned*)&h1r[row][0])[lane] = pack_bf2(acc.x, acc.y);
    }
    __syncthreads();
    // 4 waves x 1 column-tile of 16 = 64 padded output columns
    {
        int m = lane & 15, q = lane >> 4;
        bf16x8 A[4];
#pragma unroll
        for (int kt = 0; kt < 4; kt++)
            A[kt] = *(const bf16x8*)(&h1r[m][q * 8 + kt * 32]);
        int c = wave;
        f32x4 acc = {0.f, 0.f, 0.f, 0.f};
        const __hip_bfloat16* brow = w2t + (size_t)(c * 16 + m) * F_HID + q * 8;
#pragma unroll
        for (int kt = 0; kt < 4; kt++) {
            bf16x8 B = *(const bf16x8*)(brow + kt * 32);
            acc = __builtin_amdgcn_mfma_f32_16x16x32_bf16(A[kt], B, acc, 0, 0, 0);
        }
        int col = c * 16 + m;
#pragma unroll
        for (int r = 0; r < 4; r++)
            h2b[(size_t)(node0 + q * 4 + r) * F_OUT_P + col] = __float2bfloat16(acc[r]);
    }
}

// ---- 6. fused layer-2 aggregate + self-loop + bias + log_softmax.
//         Same pipelined edge loop; h2b rows are one 128B line.
__global__ void k_agg2f(const int* __restrict__ rowptr, const unsigned* __restrict__ srcw,
                        const float* __restrict__ dinv,
                        const unsigned short* __restrict__ h2b,
                        const float* __restrict__ b2, float* __restrict__ out) {
    int wave = threadIdx.x >> 6, lane = threadIdx.x & 63;
    int node = blockIdx.x * 4 + wave;
    float di = dinv[node];
    int beg = __builtin_amdgcn_readfirstlane(rowptr[node]);
    int end = __builtin_amdgcn_readfirstlane(rowptr[node + 1]);
    float acc = bf16u_to_f32(h2b[(size_t)node * F_OUT_P + lane]) * di * di;
    int e = beg;
    int nfull = (end - e) >> 3;
    if (nfull > 0) {
        unsigned pc[8]; float vc[8];
#pragma unroll
        for (int j = 0; j < 8; j++) pc[j] = srcw[e + j];
#pragma unroll
        for (int j = 0; j < 8; j++)
            vc[j] = bf16u_to_f32(h2b[(size_t)(pc[j] & 0xFFFFu) * F_OUT_P + lane]);
        e += 8;
        for (int k = 1; k < nfull; k++) {
            unsigned pn[8]; float vn[8];
#pragma unroll
            for (int j = 0; j < 8; j++) pn[j] = srcw[e + j];
#pragma unroll
            for (int j = 0; j < 8; j++)
                vn[j] = bf16u_to_f32(h2b[(size_t)(pn[j] & 0xFFFFu) * F_OUT_P + lane]);
            e += 8;
#pragma unroll
            for (int j = 0; j < 8; j++)
                acc += vc[j] * h16_to_f32(pc[j] >> 16);
#pragma unroll
            for (int j = 0; j < 8; j++) { pc[j] = pn[j]; vc[j] = vn[j]; }
        }
#pragma unroll
        for (int j = 0; j < 8; j++)
            acc += vc[j] * h16_to_f32(pc[j] >> 16);
    }
    for (; e < end; e++) {
        unsigned p = srcw[e];
        acc += bf16u_to_f32(h2b[(size_t)(p & 0xFFFFu) * F_OUT_P + lane]) * h16_to_f32(p >> 16);
    }
    float v = (lane < F_OUT) ? acc + b2[lane] : -INFINITY;
    float m = v;
    for (int off = 32; off; off >>= 1) m = fmaxf(m, __shfl_xor(m, off));
    float ex = (lane < F_OUT) ? __expf(v - m) : 0.f;
    float ssum = ex;
    for (int off = 32; off; off >>= 1) ssum += __shfl_xor(ssum, off);
    float ls = __logf(ssum);
    if (lane < F_OUT)
        out[(size_t)node * F_OUT + lane] = v - m - ls;
}

extern "C" void kernel_launch(void* const* d_in, const int* in_sizes, int n_in,
                              void* d_out, int out_size, void* d_ws, size_t ws_size,
                              hipStream_t stream) {
    const float* x  = (const float*)d_in[0];
    const float* W1 = (const float*)d_in[1];
    const float* b1 = (const float*)d_in[2];
    const float* W2 = (const float*)d_in[3];
    const float* b2 = (const float*)d_in[4];
    const unsigned int* ew = (const unsigned int*)d_in[5];
    float* out = (float*)d_out;

    // workspace (~27 MB)
    char* ws = (char*)d_ws;
    int*   flag     = (int*)ws;   ws += 256;
    int*   gcnt     = (int*)ws;   ws += 512;
    float* dinv     = (float*)ws; ws += ((N_NODES * 4 + 255) / 256) * 256;
    int*   rowptr   = (int*)ws;   ws += (((N_NODES + 1) * 4 + 255) / 256) * 256;
    unsigned* gbin  = (unsigned*)ws; ws += (size_t)NBIN * GBIN_CAP * 4;   // 3.6 MB
    unsigned* srcw  = (unsigned*)ws; ws += (size_t)N_EDGES * 4;           // 3.2 MB
    __hip_bfloat16* w1t  = (__hip_bfloat16*)ws; ws += F_IN * F_HID * 2;
    __hip_bfloat16* w2t  = (__hip_bfloat16*)ws; ws += F_OUT_P * F_HID * 2;
    __hip_bfloat16* h1b  = (__hip_bfloat16*)ws; ws += (size_t)N_NODES * F_HID * 2;  // row-major
    __hip_bfloat16* h2b  = (__hip_bfloat16*)ws; ws += (size_t)N_NODES * F_OUT_P * 2; // 6.4 MB

    k_init   <<<CVT_BLOCKS + 1, 256, 0, stream>>>(ew, W1, W2, w1t, w2t, flag, gcnt);
    k_bing1  <<<BIN_BLOCKS + G1_BLOCKS, 256, 0, stream>>>(ew, flag, gcnt, gbin, x, w1t, h1b);
    k_passB1 <<<NBIN, 256, 0, stream>>>(gcnt, gbin, rowptr, dinv);
    k_passB2 <<<NBIN, 256, 0, stream>>>(gcnt, gbin, rowptr, dinv, srcw);
    k_agg1g2 <<<N_NODES / 16, 256, 0, stream>>>(rowptr, srcw, dinv, h1b, b1, w2t, h2b);
    k_agg2f  <<<N_NODES / 4, 256, 0, stream>>>(rowptr, srcw, dinv,
                                               (const unsigned short*)h2b, b2, out);
}

// Round 12
// 199.833 us; speedup vs baseline: 1.0512x; 1.0446x over previous
//
#include <hip/hip_runtime.h>
#include <hip/hip_bf16.h>

#define N_NODES 50000
#define N_EDGES 800000
#define F_IN    128
#define F_HID   128
#define F_OUT   40
#define F_OUT_P 64                            // h2b padded stride (1 cache line)
#define N_TILES (N_NODES / 16)                // 3125 (exact)

#define NBIN      98                          // bins of 512 nodes (dst >> 9)
#define BIN_SHIFT 9
#define EPB       2048                        // edges per bin block
#define CAP       64                          // LDS slots per bin (avg ~21, P(>64)~0)
#define GBIN_CAP  9216                        // global slots per bin

#define CVT_BLOCKS ((F_IN * F_HID + F_OUT_P * F_HID) / 256)   // 96
#define BIN_BLOCKS ((N_EDGES + EPB - 1) / EPB)           // 391
#define G1_BLOCKS  ((N_TILES + 3) / 4)                   // 782

typedef __attribute__((ext_vector_type(8))) short bf16x8;   // 8 bf16 = 4 VGPRs
typedef __attribute__((ext_vector_type(4))) float f32x4;

__device__ __forceinline__ float2 unpack_bf2(unsigned u) {
    float2 r;
    r.x = __uint_as_float(u << 16);
    r.y = __uint_as_float(u & 0xffff0000u);
    return r;
}
__device__ __forceinline__ unsigned pack_bf2(float x, float y) {
    union { unsigned u; __hip_bfloat16 h[2]; } cv;
    cv.h[0] = __float2bfloat16(x);
    cv.h[1] = __float2bfloat16(y);
    return cv.u;
}
__device__ __forceinline__ short bfraw(float v) {
    __hip_bfloat16 h = __float2bfloat16(v);
    return *(short*)&h;
}
__device__ __forceinline__ float bf16u_to_f32(unsigned short us) {
    return __uint_as_float(((unsigned)us) << 16);
}
__device__ __forceinline__ unsigned f32_to_h16(float v) {
    _Float16 h = (_Float16)v;
    return (unsigned)*(unsigned short*)&h;
}
__device__ __forceinline__ float h16_to_f32(unsigned bits) {
    unsigned short us = (unsigned short)bits;
    _Float16 h = *(_Float16*)&us;
    return (float)h;
}

__device__ __forceinline__ int ld_src(const unsigned int* w, int is64, int e) {
    return is64 ? (int)w[2 * e] : (int)w[e];
}
__device__ __forceinline__ int ld_dst(const unsigned int* w, int is64, int e) {
    return is64 ? (int)w[2 * (N_EDGES + e)] : (int)w[N_EDGES + e];
}

// ---- 1. init: blocks 0..95 convert W1/W2 to transposed bf16 (W2 padded to 64
//         rows); block 96 sniffs index width and zeroes gcnt.
__global__ void k_init(const unsigned int* __restrict__ ew,
                       const float* __restrict__ W1, const float* __restrict__ W2,
                       __hip_bfloat16* __restrict__ w1t, __hip_bfloat16* __restrict__ w2t,
                       int* __restrict__ flag, int* __restrict__ gcnt) {
    int b = blockIdx.x, t = threadIdx.x;
    if (b < CVT_BLOCKS) {
        int idx = b * 256 + t;
        if (idx < F_IN * F_HID) {
            int n = idx >> 7, k = idx & 127;
            w1t[idx] = __float2bfloat16(W1[k * F_HID + n]);
        } else {
            int j = idx - F_IN * F_HID;          // 0 .. 8191
            int n = j >> 7, k = j & 127;         // n: 0 .. 63
            w2t[j] = __float2bfloat16(n < F_OUT ? W2[k * F_OUT + n] : 0.f);
        }
        return;
    }
    __shared__ int nz;
    if (t == 0) nz = 0;
    __syncthreads();
    int local = 0;
    for (int i = t; i < 4096; i += 256)
        if (ew[2 * i + 1] != 0u) local = 1;
    if (local) atomicOr(&nz, 1);
    if (t < NBIN) gcnt[t] = 0;
    __syncthreads();
    if (t == 0) flag[0] = (nz == 0) ? 1 : 0;     // 1 => int64 layout
}

// ---- 2. merged: blocks [0,391) bin 2048 edges each (2x less per-block
//         overhead, 2x larger flush runs); blocks [391,1173) MFMA gemm1.
__global__ void k_bing1(const unsigned int* __restrict__ ew, const int* __restrict__ flag,
                        int* __restrict__ gcnt, unsigned* __restrict__ gbin,
                        const float* __restrict__ x, const __hip_bfloat16* __restrict__ w1t,
                        __hip_bfloat16* __restrict__ h1b) {
    __shared__ unsigned buf[NBIN][CAP];        // ~25 KB (unused by gemm blocks)
    __shared__ int cnt[NBIN];
    __shared__ int base[NBIN];
    int t = threadIdx.x;
    if (blockIdx.x < BIN_BLOCKS) {
        for (int i = t; i < NBIN; i += 256) cnt[i] = 0;
        __syncthreads();
        int is64 = flag[0];
        int e0 = blockIdx.x * EPB;
        int n = min(EPB, N_EDGES - e0);
        if (n == EPB) {
            // fast path: 2 x (4 edges/thread ILP batch)
#pragma unroll
            for (int half = 0; half < 2; half++) {
                int s[4], d[4];
#pragma unroll
                for (int j = 0; j < 4; j++) {
                    int e = e0 + half * 1024 + t + j * 256;
                    s[j] = ld_src(ew, is64, e);
                    d[j] = ld_dst(ew, is64, e);
                }
#pragma unroll
                for (int j = 0; j < 4; j++) {
                    unsigned rec = (unsigned)s[j] | ((unsigned)d[j] << 16);
                    int b = d[j] >> BIN_SHIFT;
                    int c = atomicAdd(&cnt[b], 1);
                    if (c < CAP) buf[b][c] = rec;
                    else {
                        int g = atomicAdd(&gcnt[b], 1);
                        gbin[(size_t)b * GBIN_CAP + g] = rec;
                    }
                }
            }
        } else {
            for (int i = t; i < n; i += 256) {
                int e = e0 + i;
                int s = ld_src(ew, is64, e), d = ld_dst(ew, is64, e);
                unsigned rec = (unsigned)s | ((unsigned)d << 16);
                int b = d >> BIN_SHIFT;
                int c = atomicAdd(&cnt[b], 1);
                if (c < CAP) buf[b][c] = rec;
                else {
                    int g = atomicAdd(&gcnt[b], 1);
                    gbin[(size_t)b * GBIN_CAP + g] = rec;
                }
            }
        }
        __syncthreads();
        if (t < NBIN) {
            int m = min(cnt[t], CAP);
            base[t] = atomicAdd(&gcnt[t], m);
            cnt[t] = m;
        }
        __syncthreads();
        int wave = t >> 6, lane = t & 63;
        for (int b = wave; b < NBIN; b += 4) {
            int m = cnt[b], bs = base[b];
            for (int i = lane; i < m; i += 64)
                gbin[(size_t)b * GBIN_CAP + bs + i] = buf[b][i];
        }
        return;
    }
    // ---- gemm1 part
    int wave = t >> 6, lane = t & 63;
    int tile = (blockIdx.x - BIN_BLOCKS) * 4 + wave;
    if (tile >= N_TILES) return;
    int node0 = tile * 16;
    int m = lane & 15, q = lane >> 4;
    bf16x8 A[4];
    const float* arow = x + (size_t)(node0 + m) * F_IN + q * 8;
#pragma unroll
    for (int kt = 0; kt < 4; kt++) {
        float4 f0 = *(const float4*)(arow + kt * 32);
        float4 f1 = *(const float4*)(arow + kt * 32 + 4);
        bf16x8 a;
        a[0] = bfraw(f0.x); a[1] = bfraw(f0.y); a[2] = bfraw(f0.z); a[3] = bfraw(f0.w);
        a[4] = bfraw(f1.x); a[5] = bfraw(f1.y); a[6] = bfraw(f1.z); a[7] = bfraw(f1.w);
        A[kt] = a;
    }
#pragma unroll
    for (int c = 0; c < 8; c++) {
        f32x4 acc = {0.f, 0.f, 0.f, 0.f};
        const __hip_bfloat16* brow = w1t + (size_t)(c * 16 + m) * F_IN + q * 8;
#pragma unroll
        for (int kt = 0; kt < 4; kt++) {
            bf16x8 B = *(const bf16x8*)(brow + kt * 32);
            acc = __builtin_amdgcn_mfma_f32_16x16x32_bf16(A[kt], B, acc, 0, 0, 0);
        }
#pragma unroll
        for (int r = 0; r < 4; r++)
            h1b[(size_t)(node0 + q * 4 + r) * F_HID + c * 16 + m] = __float2bfloat16(acc[r]);
    }
}

// ---- 3. passB1: per-bin node histogram + scan -> rowptr, dinv.
__global__ void k_passB1(const int* __restrict__ gcnt, const unsigned* __restrict__ gbin,
                         int* __restrict__ rowptr, float* __restrict__ dinv) {
    __shared__ int c[512];
    __shared__ int s2[256];
    __shared__ int gall[NBIN];
    __shared__ int bbase;
    int t = threadIdx.x;
    int b = blockIdx.x;
    c[t] = 0; c[t + 256] = 0;
    if (t < NBIN) gall[t] = gcnt[t];
    __syncthreads();
    if (t == 0) {
        int s = 0;
        for (int i = 0; i < b; i++) s += gall[i];
        bbase = s;
    }
    int n = gall[b];
    const unsigned* rec = gbin + (size_t)b * GBIN_CAP;
    int base512 = b << BIN_SHIFT;
    for (int i = t; i < n; i += 256)
        atomicAdd(&c[(int)(rec[i] >> 16) - base512], 1);
    __syncthreads();
    int a0 = c[2 * t], a1 = c[2 * t + 1];
    s2[t] = a0 + a1;
    __syncthreads();
    for (int off = 1; off < 256; off <<= 1) {
        int u = (t >= off) ? s2[t - off] : 0;
        __syncthreads();
        s2[t] += u;
        __syncthreads();
    }
    int ebase = bbase + s2[t] - a0 - a1;
    int i0 = base512 + 2 * t, i1 = i0 + 1;
    if (i0 < N_NODES) { rowptr[i0] = ebase;      dinv[i0] = rsqrtf((float)a0 + 1.f); }
    if (i1 < N_NODES) { rowptr[i1] = ebase + a0; dinv[i1] = rsqrtf((float)a1 + 1.f); }
    if (b == 0 && t == 0) rowptr[N_NODES] = N_EDGES;
}

// ---- 4. passB2: scatter bin records to final CSR slots (f16 weight packed).
__global__ void k_passB2(const int* __restrict__ gcnt, const unsigned* __restrict__ gbin,
                         const int* __restrict__ rowptr, const float* __restrict__ dinv,
                         unsigned* __restrict__ srcw) {
    __shared__ int pos[512];
    __shared__ float dloc[512];
    int t = threadIdx.x;
    int b = blockIdx.x;
    int base512 = b << BIN_SHIFT;
#pragma unroll
    for (int k = 0; k < 2; k++) {
        int j = t + k * 256;
        int i = base512 + j;
        pos[j]  = (i < N_NODES) ? rowptr[i] : 0;
        dloc[j] = (i < N_NODES) ? dinv[i] : 0.f;
    }
    __syncthreads();
    int n = gcnt[b];
    const unsigned* rec = gbin + (size_t)b * GBIN_CAP;
    for (int i = t; i < n; i += 256) {
        unsigned r = rec[i];
        int s  = (int)(r & 0xFFFFu);
        int dl = (int)(r >> 16) - base512;
        int slot = atomicAdd(&pos[dl], 1);
        float norm = dinv[s] * dloc[dl];
        srcw[slot] = (unsigned)s | (f32_to_h16(norm) << 16);
    }
}

// ---- 5. fused layer-1 aggregate + self-loop + bias + relu + gemm2 for a
//         16-node tile (weighted records; h1r staged in LDS; 4 waves MFMA
//         over 64 padded output columns).
__global__ void k_agg1g2(const int* __restrict__ rowptr, const unsigned* __restrict__ srcw,
                         const float* __restrict__ dinv, const __hip_bfloat16* __restrict__ h1b,
                         const float* __restrict__ b1, const __hip_bfloat16* __restrict__ w2t,
                         __hip_bfloat16* __restrict__ h2b) {
    __shared__ __align__(16) short h1r[16][136];   // +8 bf16 pad
    int t = threadIdx.x, wave = t >> 6, lane = t & 63;
    int node0 = blockIdx.x * 16;
    const unsigned* h1u = (const unsigned*)h1b;
#pragma unroll
    for (int i = 0; i < 4; i++) {
        int row = wave * 4 + i;
        int node = node0 + row;
        float di = dinv[node];
        int beg = __builtin_amdgcn_readfirstlane(rowptr[node]);
        int end = __builtin_amdgcn_readfirstlane(rowptr[node + 1]);
        float2 acc = unpack_bf2(h1u[(size_t)node * 64 + lane]);
        float w0 = di * di;
        acc.x *= w0; acc.y *= w0;
        int e = beg;
        for (; e + 7 < end; e += 8) {
            unsigned p[8];
#pragma unroll
            for (int j = 0; j < 8; j++) p[j] = srcw[e + j];       // uniform -> s_load
            unsigned u[8];
#pragma unroll
            for (int j = 0; j < 8; j++)
                u[j] = h1u[(size_t)(p[j] & 0xFFFFu) * 64 + lane];
#pragma unroll
            for (int j = 0; j < 8; j++) {
                float w = h16_to_f32(p[j] >> 16);
                float2 v = unpack_bf2(u[j]);
                acc.x += v.x * w;
                acc.y += v.y * w;
            }
        }
        for (; e < end; e++) {
            unsigned p = srcw[e];
            float w = h16_to_f32(p >> 16);
            float2 v = unpack_bf2(h1u[(size_t)(p & 0xFFFFu) * 64 + lane]);
            acc.x += v.x * w;
            acc.y += v.y * w;
        }
        float2 bb = ((const float2*)b1)[lane];
        acc.x = fmaxf(acc.x + bb.x, 0.f);
        acc.y = fmaxf(acc.y + bb.y, 0.f);
        ((unsigned*)&h1r[row][0])[lane] = pack_bf2(acc.x, acc.y);
    }
    __syncthreads();
    {
        int m = lane & 15, q = lane >> 4;
        bf16x8 A[4];
#pragma unroll
        for (int kt = 0; kt < 4; kt++)
            A[kt] = *(const bf16x8*)(&h1r[m][q * 8 + kt * 32]);
        int c = wave;
        f32x4 acc = {0.f, 0.f, 0.f, 0.f};
        const __hip_bfloat16* brow = w2t + (size_t)(c * 16 + m) * F_HID + q * 8;
#pragma unroll
        for (int kt = 0; kt < 4; kt++) {
            bf16x8 B = *(const bf16x8*)(brow + kt * 32);
            acc = __builtin_amdgcn_mfma_f32_16x16x32_bf16(A[kt], B, acc, 0, 0, 0);
        }
        int col = c * 16 + m;
#pragma unroll
        for (int r = 0; r < 4; r++)
            h2b[(size_t)(node0 + q * 4 + r) * F_OUT_P + col] = __float2bfloat16(acc[r]);
    }
}

// ---- 6. fused layer-2 aggregate + self-loop + bias + log_softmax.
//         h2b rows are 64 bf16 = one 128B line; all 64 lanes load.
__global__ void k_agg2f(const int* __restrict__ rowptr, const unsigned* __restrict__ srcw,
                        const float* __restrict__ dinv,
                        const unsigned short* __restrict__ h2b,
                        const float* __restrict__ b2, float* __restrict__ out) {
    int wave = threadIdx.x >> 6, lane = threadIdx.x & 63;
    int node = blockIdx.x * 4 + wave;
    float di = dinv[node];
    int beg = __builtin_amdgcn_readfirstlane(rowptr[node]);
    int end = __builtin_amdgcn_readfirstlane(rowptr[node + 1]);
    float acc = bf16u_to_f32(h2b[(size_t)node * F_OUT_P + lane]) * di * di;
    int e = beg;
    for (; e + 7 < end; e += 8) {
        unsigned p[8];
#pragma unroll
        for (int j = 0; j < 8; j++) p[j] = srcw[e + j];          // uniform -> s_load
        float v[8];
#pragma unroll
        for (int j = 0; j < 8; j++)
            v[j] = bf16u_to_f32(h2b[(size_t)(p[j] & 0xFFFFu) * F_OUT_P + lane]);
#pragma unroll
        for (int j = 0; j < 8; j++)
            acc += v[j] * h16_to_f32(p[j] >> 16);
    }
    for (; e < end; e++) {
        unsigned p = srcw[e];
        acc += bf16u_to_f32(h2b[(size_t)(p & 0xFFFFu) * F_OUT_P + lane]) * h16_to_f32(p >> 16);
    }
    float v = (lane < F_OUT) ? acc + b2[lane] : -INFINITY;
    float m = v;
    for (int off = 32; off; off >>= 1) m = fmaxf(m, __shfl_xor(m, off));
    float ex = (lane < F_OUT) ? __expf(v - m) : 0.f;
    float ssum = ex;
    for (int off = 32; off; off >>= 1) ssum += __shfl_xor(ssum, off);
    float ls = __logf(ssum);
    if (lane < F_OUT)
        out[(size_t)node * F_OUT + lane] = v - m - ls;
}

extern "C" void kernel_launch(void* const* d_in, const int* in_sizes, int n_in,
                              void* d_out, int out_size, void* d_ws, size_t ws_size,
                              hipStream_t stream) {
    const float* x  = (const float*)d_in[0];
    const float* W1 = (const float*)d_in[1];
    const float* b1 = (const float*)d_in[2];
    const float* W2 = (const float*)d_in[3];
    const float* b2 = (const float*)d_in[4];
    const unsigned int* ew = (const unsigned int*)d_in[5];
    float* out = (float*)d_out;

    // workspace (~27 MB)
    char* ws = (char*)d_ws;
    int*   flag     = (int*)ws;   ws += 256;
    int*   gcnt     = (int*)ws;   ws += 512;
    float* dinv     = (float*)ws; ws += ((N_NODES * 4 + 255) / 256) * 256;
    int*   rowptr   = (int*)ws;   ws += (((N_NODES + 1) * 4 + 255) / 256) * 256;
    unsigned* gbin  = (unsigned*)ws; ws += (size_t)NBIN * GBIN_CAP * 4;   // 3.6 MB
    unsigned* srcw  = (unsigned*)ws; ws += (size_t)N_EDGES * 4;           // 3.2 MB
    __hip_bfloat16* w1t  = (__hip_bfloat16*)ws; ws += F_IN * F_HID * 2;
    __hip_bfloat16* w2t  = (__hip_bfloat16*)ws; ws += F_OUT_P * F_HID * 2;
    __hip_bfloat16* h1b  = (__hip_bfloat16*)ws; ws += (size_t)N_NODES * F_HID * 2;  // row-major
    __hip_bfloat16* h2b  = (__hip_bfloat16*)ws; ws += (size_t)N_NODES * F_OUT_P * 2; // 6.4 MB

    k_init   <<<CVT_BLOCKS + 1, 256, 0, stream>>>(ew, W1, W2, w1t, w2t, flag, gcnt);
    k_bing1  <<<BIN_BLOCKS + G1_BLOCKS, 256, 0, stream>>>(ew, flag, gcnt, gbin, x, w1t, h1b);
    k_passB1 <<<NBIN, 256, 0, stream>>>(gcnt, gbin, rowptr, dinv);
    k_passB2 <<<NBIN, 256, 0, stream>>>(gcnt, gbin, rowptr, dinv, srcw);
    k_agg1g2 <<<N_NODES / 16, 256, 0, stream>>>(rowptr, srcw, dinv, h1b, b1, w2t, h2b);
    k_agg2f  <<<N_NODES / 4, 256, 0, stream>>>(rowptr, srcw, dinv,
                                               (const unsigned short*)h2b, b2, out);
}

// Round 13
// 196.792 us; speedup vs baseline: 1.0675x; 1.0155x over previous
//
#include <hip/hip_runtime.h>
#include <hip/hip_bf16.h>

#define N_NODES 50000
#define N_EDGES 800000
#define F_IN    128
#define F_HID   128
#define F_OUT   40
#define F_OUT_P 64                            // h2b padded stride (1 cache line)
#define N_TILES (N_NODES / 16)                // 3125 (exact)

#define NBIN      98                          // bins of 512 nodes (dst >> 9)
#define BIN_SHIFT 9
#define EPB       4096                        // edges per bin block
#define CAP       64                          // LDS slots per bin (lambda~42; overflow path exact)
#define GBIN_CAP  9216                        // global slots per bin

#define CVT_BLOCKS ((F_IN * F_HID + F_OUT_P * F_HID) / 256)   // 96
#define BIN_BLOCKS ((N_EDGES + EPB - 1) / EPB)           // 196
#define G1_BLOCKS  ((N_TILES + 3) / 4)                   // 782

typedef __attribute__((ext_vector_type(8))) short bf16x8;   // 8 bf16 = 4 VGPRs
typedef __attribute__((ext_vector_type(4))) float f32x4;

__device__ __forceinline__ float2 unpack_bf2(unsigned u) {
    float2 r;
    r.x = __uint_as_float(u << 16);
    r.y = __uint_as_float(u & 0xffff0000u);
    return r;
}
__device__ __forceinline__ unsigned pack_bf2(float x, float y) {
    union { unsigned u; __hip_bfloat16 h[2]; } cv;
    cv.h[0] = __float2bfloat16(x);
    cv.h[1] = __float2bfloat16(y);
    return cv.u;
}
__device__ __forceinline__ short bfraw(float v) {
    __hip_bfloat16 h = __float2bfloat16(v);
    return *(short*)&h;
}
__device__ __forceinline__ float bf16u_to_f32(unsigned short us) {
    return __uint_as_float(((unsigned)us) << 16);
}
__device__ __forceinline__ unsigned f32_to_h16(float v) {
    _Float16 h = (_Float16)v;
    return (unsigned)*(unsigned short*)&h;
}
__device__ __forceinline__ float h16_to_f32(unsigned bits) {
    unsigned short us = (unsigned short)bits;
    _Float16 h = *(_Float16*)&us;
    return (float)h;
}

__device__ __forceinline__ int ld_src(const unsigned int* w, int is64, int e) {
    return is64 ? (int)w[2 * e] : (int)w[e];
}
__device__ __forceinline__ int ld_dst(const unsigned int* w, int is64, int e) {
    return is64 ? (int)w[2 * (N_EDGES + e)] : (int)w[N_EDGES + e];
}

// ---- 1. init: blocks 0..95 convert W1/W2 to transposed bf16 (W2 padded to 64
//         rows); block 96 sniffs index width and zeroes gcnt.
__global__ void k_init(const unsigned int* __restrict__ ew,
                       const float* __restrict__ W1, const float* __restrict__ W2,
                       __hip_bfloat16* __restrict__ w1t, __hip_bfloat16* __restrict__ w2t,
                       int* __restrict__ flag, int* __restrict__ gcnt) {
    int b = blockIdx.x, t = threadIdx.x;
    if (b < CVT_BLOCKS) {
        int idx = b * 256 + t;
        if (idx < F_IN * F_HID) {
            int n = idx >> 7, k = idx & 127;
            w1t[idx] = __float2bfloat16(W1[k * F_HID + n]);
        } else {
            int j = idx - F_IN * F_HID;          // 0 .. 8191
            int n = j >> 7, k = j & 127;         // n: 0 .. 63
            w2t[j] = __float2bfloat16(n < F_OUT ? W2[k * F_OUT + n] : 0.f);
        }
        return;
    }
    __shared__ int nz;
    if (t == 0) nz = 0;
    __syncthreads();
    int local = 0;
    for (int i = t; i < 4096; i += 256)
        if (ew[2 * i + 1] != 0u) local = 1;
    if (local) atomicOr(&nz, 1);
    if (t < NBIN) gcnt[t] = 0;
    __syncthreads();
    if (t == 0) flag[0] = (nz == 0) ? 1 : 0;     // 1 => int64 layout
}

// ---- 2. merged: blocks [0,196) bin 4096 edges each; blocks [196,978) MFMA gemm1.
__global__ void k_bing1(const unsigned int* __restrict__ ew, const int* __restrict__ flag,
                        int* __restrict__ gcnt, unsigned* __restrict__ gbin,
                        const float* __restrict__ x, const __hip_bfloat16* __restrict__ w1t,
                        __hip_bfloat16* __restrict__ h1b) {
    __shared__ unsigned buf[NBIN][CAP];        // 25.1 KB (unused by gemm blocks)
    __shared__ int cnt[NBIN];
    __shared__ int base[NBIN];
    int t = threadIdx.x;
    if (blockIdx.x < BIN_BLOCKS) {
        for (int i = t; i < NBIN; i += 256) cnt[i] = 0;
        __syncthreads();
        int is64 = flag[0];
        int e0 = blockIdx.x * EPB;
        int n = min(EPB, N_EDGES - e0);
        if (n == EPB) {
            // fast path: 4 x (4 edges/thread ILP batch)
#pragma unroll
            for (int half = 0; half < 4; half++) {
                int s[4], d[4];
#pragma unroll
                for (int j = 0; j < 4; j++) {
                    int e = e0 + half * 1024 + t + j * 256;
                    s[j] = ld_src(ew, is64, e);
                    d[j] = ld_dst(ew, is64, e);
                }
#pragma unroll
                for (int j = 0; j < 4; j++) {
                    unsigned rec = (unsigned)s[j] | ((unsigned)d[j] << 16);
                    int b = d[j] >> BIN_SHIFT;
                    int c = atomicAdd(&cnt[b], 1);
                    if (c < CAP) buf[b][c] = rec;
                    else {
                        int g = atomicAdd(&gcnt[b], 1);
                        gbin[(size_t)b * GBIN_CAP + g] = rec;
                    }
                }
            }
        } else {
            for (int i = t; i < n; i += 256) {
                int e = e0 + i;
                int s = ld_src(ew, is64, e), d = ld_dst(ew, is64, e);
                unsigned rec = (unsigned)s | ((unsigned)d << 16);
                int b = d >> BIN_SHIFT;
                int c = atomicAdd(&cnt[b], 1);
                if (c < CAP) buf[b][c] = rec;
                else {
                    int g = atomicAdd(&gcnt[b], 1);
                    gbin[(size_t)b * GBIN_CAP + g] = rec;
                }
            }
        }
        __syncthreads();
        if (t < NBIN) {
            int m = min(cnt[t], CAP);
            base[t] = atomicAdd(&gcnt[t], m);
            cnt[t] = m;
        }
        __syncthreads();
        int wave = t >> 6, lane = t & 63;
        for (int b = wave; b < NBIN; b += 4) {
            int m = cnt[b], bs = base[b];
            for (int i = lane; i < m; i += 64)
                gbin[(size_t)b * GBIN_CAP + bs + i] = buf[b][i];
        }
        return;
    }
    // ---- gemm1 part
    int wave = t >> 6, lane = t & 63;
    int tile = (blockIdx.x - BIN_BLOCKS) * 4 + wave;
    if (tile >= N_TILES) return;
    int node0 = tile * 16;
    int m = lane & 15, q = lane >> 4;
    bf16x8 A[4];
    const float* arow = x + (size_t)(node0 + m) * F_IN + q * 8;
#pragma unroll
    for (int kt = 0; kt < 4; kt++) {
        float4 f0 = *(const float4*)(arow + kt * 32);
        float4 f1 = *(const float4*)(arow + kt * 32 + 4);
        bf16x8 a;
        a[0] = bfraw(f0.x); a[1] = bfraw(f0.y); a[2] = bfraw(f0.z); a[3] = bfraw(f0.w);
        a[4] = bfraw(f1.x); a[5] = bfraw(f1.y); a[6] = bfraw(f1.z); a[7] = bfraw(f1.w);
        A[kt] = a;
    }
#pragma unroll
    for (int c = 0; c < 8; c++) {
        f32x4 acc = {0.f, 0.f, 0.f, 0.f};
        const __hip_bfloat16* brow = w1t + (size_t)(c * 16 + m) * F_IN + q * 8;
#pragma unroll
        for (int kt = 0; kt < 4; kt++) {
            bf16x8 B = *(const bf16x8*)(brow + kt * 32);
            acc = __builtin_amdgcn_mfma_f32_16x16x32_bf16(A[kt], B, acc, 0, 0, 0);
        }
#pragma unroll
        for (int r = 0; r < 4; r++)
            h1b[(size_t)(node0 + q * 4 + r) * F_HID + c * 16 + m] = __float2bfloat16(acc[r]);
    }
}

// ---- 3. passB1: per-bin node histogram + scan -> rowptr, dinv.
__global__ void k_passB1(const int* __restrict__ gcnt, const unsigned* __restrict__ gbin,
                         int* __restrict__ rowptr, float* __restrict__ dinv) {
    __shared__ int c[512];
    __shared__ int s2[256];
    __shared__ int gall[NBIN];
    __shared__ int bbase;
    int t = threadIdx.x;
    int b = blockIdx.x;
    c[t] = 0; c[t + 256] = 0;
    if (t < NBIN) gall[t] = gcnt[t];
    __syncthreads();
    if (t == 0) {
        int s = 0;
        for (int i = 0; i < b; i++) s += gall[i];
        bbase = s;
    }
    int n = gall[b];
    const unsigned* rec = gbin + (size_t)b * GBIN_CAP;
    int base512 = b << BIN_SHIFT;
    for (int i = t; i < n; i += 256)
        atomicAdd(&c[(int)(rec[i] >> 16) - base512], 1);
    __syncthreads();
    int a0 = c[2 * t], a1 = c[2 * t + 1];
    s2[t] = a0 + a1;
    __syncthreads();
    for (int off = 1; off < 256; off <<= 1) {
        int u = (t >= off) ? s2[t - off] : 0;
        __syncthreads();
        s2[t] += u;
        __syncthreads();
    }
    int ebase = bbase + s2[t] - a0 - a1;
    int i0 = base512 + 2 * t, i1 = i0 + 1;
    if (i0 < N_NODES) { rowptr[i0] = ebase;      dinv[i0] = rsqrtf((float)a0 + 1.f); }
    if (i1 < N_NODES) { rowptr[i1] = ebase + a0; dinv[i1] = rsqrtf((float)a1 + 1.f); }
    if (b == 0 && t == 0) rowptr[N_NODES] = N_EDGES;
}

// ---- 4. passB2: scatter bin records to final CSR slots (f16 weight packed).
__global__ void k_passB2(const int* __restrict__ gcnt, const unsigned* __restrict__ gbin,
                         const int* __restrict__ rowptr, const float* __restrict__ dinv,
                         unsigned* __restrict__ srcw) {
    __shared__ int pos[512];
    __shared__ float dloc[512];
    int t = threadIdx.x;
    int b = blockIdx.x;
    int base512 = b << BIN_SHIFT;
#pragma unroll
    for (int k = 0; k < 2; k++) {
        int j = t + k * 256;
        int i = base512 + j;
        pos[j]  = (i < N_NODES) ? rowptr[i] : 0;
        dloc[j] = (i < N_NODES) ? dinv[i] : 0.f;
    }
    __syncthreads();
    int n = gcnt[b];
    const unsigned* rec = gbin + (size_t)b * GBIN_CAP;
    for (int i = t; i < n; i += 256) {
        unsigned r = rec[i];
        int s  = (int)(r & 0xFFFFu);
        int dl = (int)(r >> 16) - base512;
        int slot = atomicAdd(&pos[dl], 1);
        float norm = dinv[s] * dloc[dl];
        srcw[slot] = (unsigned)s | (f32_to_h16(norm) << 16);
    }
}

// ---- 5. fused layer-1 aggregate + self-loop + bias + relu + gemm2 for a
//         16-node tile (weighted records; h1r staged in LDS; 4 waves MFMA
//         over 64 padded output columns).
__global__ void k_agg1g2(const int* __restrict__ rowptr, const unsigned* __restrict__ srcw,
                         const float* __restrict__ dinv, const __hip_bfloat16* __restrict__ h1b,
                         const float* __restrict__ b1, const __hip_bfloat16* __restrict__ w2t,
                         __hip_bfloat16* __restrict__ h2b) {
    __shared__ __align__(16) short h1r[16][136];   // +8 bf16 pad
    int t = threadIdx.x, wave = t >> 6, lane = t & 63;
    int node0 = blockIdx.x * 16;
    const unsigned* h1u = (const unsigned*)h1b;
#pragma unroll
    for (int i = 0; i < 4; i++) {
        int row = wave * 4 + i;
        int node = node0 + row;
        float di = dinv[node];
        int beg = __builtin_amdgcn_readfirstlane(rowptr[node]);
        int end = __builtin_amdgcn_readfirstlane(rowptr[node + 1]);
        float2 acc = unpack_bf2(h1u[(size_t)node * 64 + lane]);
        float w0 = di * di;
        acc.x *= w0; acc.y *= w0;
        int e = beg;
        for (; e + 7 < end; e += 8) {
            unsigned p[8];
#pragma unroll
            for (int j = 0; j < 8; j++) p[j] = srcw[e + j];       // uniform -> s_load
            unsigned u[8];
#pragma unroll
            for (int j = 0; j < 8; j++)
                u[j] = h1u[(size_t)(p[j] & 0xFFFFu) * 64 + lane];
#pragma unroll
            for (int j = 0; j < 8; j++) {
                float w = h16_to_f32(p[j] >> 16);
                float2 v = unpack_bf2(u[j]);
                acc.x += v.x * w;
                acc.y += v.y * w;
            }
        }
        for (; e < end; e++) {
            unsigned p = srcw[e];
            float w = h16_to_f32(p >> 16);
            float2 v = unpack_bf2(h1u[(size_t)(p & 0xFFFFu) * 64 + lane]);
            acc.x += v.x * w;
            acc.y += v.y * w;
        }
        float2 bb = ((const float2*)b1)[lane];
        acc.x = fmaxf(acc.x + bb.x, 0.f);
        acc.y = fmaxf(acc.y + bb.y, 0.f);
        ((unsigned*)&h1r[row][0])[lane] = pack_bf2(acc.x, acc.y);
    }
    __syncthreads();
    {
        int m = lane & 15, q = lane >> 4;
        bf16x8 A[4];
#pragma unroll
        for (int kt = 0; kt < 4; kt++)
            A[kt] = *(const bf16x8*)(&h1r[m][q * 8 + kt * 32]);
        int c = wave;
        f32x4 acc = {0.f, 0.f, 0.f, 0.f};
        const __hip_bfloat16* brow = w2t + (size_t)(c * 16 + m) * F_HID + q * 8;
#pragma unroll
        for (int kt = 0; kt < 4; kt++) {
            bf16x8 B = *(const bf16x8*)(brow + kt * 32);
            acc = __builtin_amdgcn_mfma_f32_16x16x32_bf16(A[kt], B, acc, 0, 0, 0);
        }
        int col = c * 16 + m;
#pragma unroll
        for (int r = 0; r < 4; r++)
            h2b[(size_t)(node0 + q * 4 + r) * F_OUT_P + col] = __float2bfloat16(acc[r]);
    }
}

// ---- 6. fused layer-2 aggregate + self-loop + bias + log_softmax.
//         h2b rows are 64 bf16 = one 128B line; all 64 lanes load.
__global__ void k_agg2f(const int* __restrict__ rowptr, const unsigned* __restrict__ srcw,
                        const float* __restrict__ dinv,
                        const unsigned short* __restrict__ h2b,
                        const float* __restrict__ b2, float* __restrict__ out) {
    int wave = threadIdx.x >> 6, lane = threadIdx.x & 63;
    int node = blockIdx.x * 4 + wave;
    float di = dinv[node];
    int beg = __builtin_amdgcn_readfirstlane(rowptr[node]);
    int end = __builtin_amdgcn_readfirstlane(rowptr[node + 1]);
    float acc = bf16u_to_f32(h2b[(size_t)node * F_OUT_P + lane]) * di * di;
    int e = beg;
    for (; e + 7 < end; e += 8) {
        unsigned p[8];
#pragma unroll
        for (int j = 0; j < 8; j++) p[j] = srcw[e + j];          // uniform -> s_load
        float v[8];
#pragma unroll
        for (int j = 0; j < 8; j++)
            v[j] = bf16u_to_f32(h2b[(size_t)(p[j] & 0xFFFFu) * F_OUT_P + lane]);
#pragma unroll
        for (int j = 0; j < 8; j++)
            acc += v[j] * h16_to_f32(p[j] >> 16);
    }
    for (; e < end; e++) {
        unsigned p = srcw[e];
        acc += bf16u_to_f32(h2b[(size_t)(p & 0xFFFFu) * F_OUT_P + lane]) * h16_to_f32(p >> 16);
    }
    float v = (lane < F_OUT) ? acc + b2[lane] : -INFINITY;
    float m = v;
    for (int off = 32; off; off >>= 1) m = fmaxf(m, __shfl_xor(m, off));
    float ex = (lane < F_OUT) ? __expf(v - m) : 0.f;
    float ssum = ex;
    for (int off = 32; off; off >>= 1) ssum += __shfl_xor(ssum, off);
    float ls = __logf(ssum);
    if (lane < F_OUT)
        out[(size_t)node * F_OUT + lane] = v - m - ls;
}

extern "C" void kernel_launch(void* const* d_in, const int* in_sizes, int n_in,
                              void* d_out, int out_size, void* d_ws, size_t ws_size,
                              hipStream_t stream) {
    const float* x  = (const float*)d_in[0];
    const float* W1 = (const float*)d_in[1];
    const float* b1 = (const float*)d_in[2];
    const float* W2 = (const float*)d_in[3];
    const float* b2 = (const float*)d_in[4];
    const unsigned int* ew = (const unsigned int*)d_in[5];
    float* out = (float*)d_out;

    // workspace (~27 MB)
    char* ws = (char*)d_ws;
    int*   flag     = (int*)ws;   ws += 256;
    int*   gcnt     = (int*)ws;   ws += 512;
    float* dinv     = (float*)ws; ws += ((N_NODES * 4 + 255) / 256) * 256;
    int*   rowptr   = (int*)ws;   ws += (((N_NODES + 1) * 4 + 255) / 256) * 256;
    unsigned* gbin  = (unsigned*)ws; ws += (size_t)NBIN * GBIN_CAP * 4;   // 3.6 MB
    unsigned* srcw  = (unsigned*)ws; ws += (size_t)N_EDGES * 4;           // 3.2 MB
    __hip_bfloat16* w1t  = (__hip_bfloat16*)ws; ws += F_IN * F_HID * 2;
    __hip_bfloat16* w2t  = (__hip_bfloat16*)ws; ws += F_OUT_P * F_HID * 2;
    __hip_bfloat16* h1b  = (__hip_bfloat16*)ws; ws += (size_t)N_NODES * F_HID * 2;  // row-major
    __hip_bfloat16* h2b  = (__hip_bfloat16*)ws; ws += (size_t)N_NODES * F_OUT_P * 2; // 6.4 MB

    k_init   <<<CVT_BLOCKS + 1, 256, 0, stream>>>(ew, W1, W2, w1t, w2t, flag, gcnt);
    k_bing1  <<<BIN_BLOCKS + G1_BLOCKS, 256, 0, stream>>>(ew, flag, gcnt, gbin, x, w1t, h1b);
    k_passB1 <<<NBIN, 256, 0, stream>>>(gcnt, gbin, rowptr, dinv);
    k_passB2 <<<NBIN, 256, 0, stream>>>(gcnt, gbin, rowptr, dinv, srcw);
    k_agg1g2 <<<N_NODES / 16, 256, 0, stream>>>(rowptr, srcw, dinv, h1b, b1, w2t, h2b);
    k_agg2f  <<<N_NODES / 4, 256, 0, stream>>>(rowptr, srcw, dinv,
                                               (const unsigned short*)h2b, b2, out);
}

// Round 14
// 188.483 us; speedup vs baseline: 1.1145x; 1.0441x over previous
//
#include <hip/hip_runtime.h>
#include <hip/hip_bf16.h>

#define N_NODES 50000
#define N_EDGES 800000
#define F_IN    128
#define F_HID   128
#define F_OUT   40
#define F_OUT_P 64                            // h2b padded stride (1 cache line)
#define N_TILES (N_NODES / 16)                // 3125 (exact)

#define NBIN      98                          // bins of 512 nodes (dst >> 9)
#define BIN_SHIFT 9
#define EPB       4096                        // edges per bin block
#define CAP       64                          // LDS slots per bin (lambda~42; overflow path exact)
#define GBIN_CAP  9216                        // global slots per bin

#define CVT_BLOCKS ((F_IN * F_HID + F_OUT_P * F_HID) / 256)   // 96
#define BIN_BLOCKS ((N_EDGES + EPB - 1) / EPB)           // 196
#define G1_BLOCKS  ((N_TILES + 3) / 4)                   // 782

typedef __attribute__((ext_vector_type(8))) short bf16x8;   // 8 bf16 = 4 VGPRs
typedef __attribute__((ext_vector_type(4))) float f32x4;

__device__ __forceinline__ float2 unpack_bf2(unsigned u) {
    float2 r;
    r.x = __uint_as_float(u << 16);
    r.y = __uint_as_float(u & 0xffff0000u);
    return r;
}
__device__ __forceinline__ unsigned pack_bf2(float x, float y) {
    union { unsigned u; __hip_bfloat16 h[2]; } cv;
    cv.h[0] = __float2bfloat16(x);
    cv.h[1] = __float2bfloat16(y);
    return cv.u;
}
__device__ __forceinline__ short bfraw(float v) {
    __hip_bfloat16 h = __float2bfloat16(v);
    return *(short*)&h;
}
__device__ __forceinline__ float bf16u_to_f32(unsigned short us) {
    return __uint_as_float(((unsigned)us) << 16);
}
__device__ __forceinline__ unsigned f32_to_h16(float v) {
    _Float16 h = (_Float16)v;
    return (unsigned)*(unsigned short*)&h;
}
__device__ __forceinline__ float h16_to_f32(unsigned bits) {
    unsigned short us = (unsigned short)bits;
    _Float16 h = *(_Float16*)&us;
    return (float)h;
}

__device__ __forceinline__ int ld_src(const unsigned int* w, int is64, int e) {
    return is64 ? (int)w[2 * e] : (int)w[e];
}
__device__ __forceinline__ int ld_dst(const unsigned int* w, int is64, int e) {
    return is64 ? (int)w[2 * (N_EDGES + e)] : (int)w[N_EDGES + e];
}

// ---- 1. init: blocks 0..95 convert W1/W2 to transposed bf16 (W2 padded to 64
//         rows); block 96 sniffs index width and zeroes gcnt.
__global__ void k_init(const unsigned int* __restrict__ ew,
                       const float* __restrict__ W1, const float* __restrict__ W2,
                       __hip_bfloat16* __restrict__ w1t, __hip_bfloat16* __restrict__ w2t,
                       int* __restrict__ flag, int* __restrict__ gcnt) {
    int b = blockIdx.x, t = threadIdx.x;
    if (b < CVT_BLOCKS) {
        int idx = b * 256 + t;
        if (idx < F_IN * F_HID) {
            int n = idx >> 7, k = idx & 127;
            w1t[idx] = __float2bfloat16(W1[k * F_HID + n]);
        } else {
            int j = idx - F_IN * F_HID;          // 0 .. 8191
            int n = j >> 7, k = j & 127;         // n: 0 .. 63
            w2t[j] = __float2bfloat16(n < F_OUT ? W2[k * F_OUT + n] : 0.f);
        }
        return;
    }
    __shared__ int nz;
    if (t == 0) nz = 0;
    __syncthreads();
    int local = 0;
    for (int i = t; i < 4096; i += 256)
        if (ew[2 * i + 1] != 0u) local = 1;
    if (local) atomicOr(&nz, 1);
    if (t < NBIN) gcnt[t] = 0;
    __syncthreads();
    if (t == 0) flag[0] = (nz == 0) ? 1 : 0;     // 1 => int64 layout
}

// ---- 2. merged: blocks [0,196) bin 4096 edges each; blocks [196,978) MFMA gemm1.
__global__ void k_bing1(const unsigned int* __restrict__ ew, const int* __restrict__ flag,
                        int* __restrict__ gcnt, unsigned* __restrict__ gbin,
                        const float* __restrict__ x, const __hip_bfloat16* __restrict__ w1t,
                        __hip_bfloat16* __restrict__ h1b) {
    __shared__ unsigned buf[NBIN][CAP];        // 25.1 KB (unused by gemm blocks)
    __shared__ int cnt[NBIN];
    __shared__ int base[NBIN];
    int t = threadIdx.x;
    if (blockIdx.x < BIN_BLOCKS) {
        for (int i = t; i < NBIN; i += 256) cnt[i] = 0;
        __syncthreads();
        int is64 = flag[0];
        int e0 = blockIdx.x * EPB;
        int n = min(EPB, N_EDGES - e0);
        if (n == EPB) {
            // fast path: 4 x (4 edges/thread ILP batch)
#pragma unroll
            for (int half = 0; half < 4; half++) {
                int s[4], d[4];
#pragma unroll
                for (int j = 0; j < 4; j++) {
                    int e = e0 + half * 1024 + t + j * 256;
                    s[j] = ld_src(ew, is64, e);
                    d[j] = ld_dst(ew, is64, e);
                }
#pragma unroll
                for (int j = 0; j < 4; j++) {
                    unsigned rec = (unsigned)s[j] | ((unsigned)d[j] << 16);
                    int b = d[j] >> BIN_SHIFT;
                    int c = atomicAdd(&cnt[b], 1);
                    if (c < CAP) buf[b][c] = rec;
                    else {
                        int g = atomicAdd(&gcnt[b], 1);
                        gbin[(size_t)b * GBIN_CAP + g] = rec;
                    }
                }
            }
        } else {
            for (int i = t; i < n; i += 256) {
                int e = e0 + i;
                int s = ld_src(ew, is64, e), d = ld_dst(ew, is64, e);
                unsigned rec = (unsigned)s | ((unsigned)d << 16);
                int b = d >> BIN_SHIFT;
                int c = atomicAdd(&cnt[b], 1);
                if (c < CAP) buf[b][c] = rec;
                else {
                    int g = atomicAdd(&gcnt[b], 1);
                    gbin[(size_t)b * GBIN_CAP + g] = rec;
                }
            }
        }
        __syncthreads();
        if (t < NBIN) {
            int m = min(cnt[t], CAP);
            base[t] = atomicAdd(&gcnt[t], m);
            cnt[t] = m;
        }
        __syncthreads();
        int wave = t >> 6, lane = t & 63;
        for (int b = wave; b < NBIN; b += 4) {
            int m = cnt[b], bs = base[b];
            for (int i = lane; i < m; i += 64)
                gbin[(size_t)b * GBIN_CAP + bs + i] = buf[b][i];
        }
        return;
    }
    // ---- gemm1 part
    int wave = t >> 6, lane = t & 63;
    int tile = (blockIdx.x - BIN_BLOCKS) * 4 + wave;
    if (tile >= N_TILES) return;
    int node0 = tile * 16;
    int m = lane & 15, q = lane >> 4;
    bf16x8 A[4];
    const float* arow = x + (size_t)(node0 + m) * F_IN + q * 8;
#pragma unroll
    for (int kt = 0; kt < 4; kt++) {
        float4 f0 = *(const float4*)(arow + kt * 32);
        float4 f1 = *(const float4*)(arow + kt * 32 + 4);
        bf16x8 a;
        a[0] = bfraw(f0.x); a[1] = bfraw(f0.y); a[2] = bfraw(f0.z); a[3] = bfraw(f0.w);
        a[4] = bfraw(f1.x); a[5] = bfraw(f1.y); a[6] = bfraw(f1.z); a[7] = bfraw(f1.w);
        A[kt] = a;
    }
#pragma unroll
    for (int c = 0; c < 8; c++) {
        f32x4 acc = {0.f, 0.f, 0.f, 0.f};
        const __hip_bfloat16* brow = w1t + (size_t)(c * 16 + m) * F_IN + q * 8;
#pragma unroll
        for (int kt = 0; kt < 4; kt++) {
            bf16x8 B = *(const bf16x8*)(brow + kt * 32);
            acc = __builtin_amdgcn_mfma_f32_16x16x32_bf16(A[kt], B, acc, 0, 0, 0);
        }
#pragma unroll
        for (int r = 0; r < 4; r++)
            h1b[(size_t)(node0 + q * 4 + r) * F_HID + c * 16 + m] = __float2bfloat16(acc[r]);
    }
}

// ---- 3. passB1: per-bin node histogram + scan -> rowptr, dinv.
//         512 threads/block (was 256): 2x wave parallelism for the
//         latency-bound histogram phase; scan is 1 node/thread.
__global__ void k_passB1(const int* __restrict__ gcnt, const unsigned* __restrict__ gbin,
                         int* __restrict__ rowptr, float* __restrict__ dinv) {
    __shared__ int c[512];
    __shared__ int s2[512];
    __shared__ int gall[NBIN];
    __shared__ int bbase;
    int t = threadIdx.x;                       // 0..511
    int b = blockIdx.x;
    c[t] = 0;
    if (t < NBIN) gall[t] = gcnt[t];
    __syncthreads();
    if (t == 0) {
        int s = 0;
        for (int i = 0; i < b; i++) s += gall[i];
        bbase = s;
    }
    int n = gall[b];
    const unsigned* rec = gbin + (size_t)b * GBIN_CAP;
    int base512 = b << BIN_SHIFT;
    for (int i = t; i < n; i += 512)
        atomicAdd(&c[(int)(rec[i] >> 16) - base512], 1);
    __syncthreads();
    int a0 = c[t];
    s2[t] = a0;
    __syncthreads();
    for (int off = 1; off < 512; off <<= 1) {
        int u = (t >= off) ? s2[t - off] : 0;
        __syncthreads();
        s2[t] += u;
        __syncthreads();
    }
    int ebase = bbase + s2[t] - a0;            // exclusive prefix
    int i0 = base512 + t;
    if (i0 < N_NODES) { rowptr[i0] = ebase; dinv[i0] = rsqrtf((float)a0 + 1.f); }
    if (b == 0 && t == 0) rowptr[N_NODES] = N_EDGES;
}

// ---- 4. passB2: scatter bin records to final CSR slots (f16 weight packed).
//         512 threads/block: 2x wave parallelism for the gather/scatter loop.
__global__ void k_passB2(const int* __restrict__ gcnt, const unsigned* __restrict__ gbin,
                         const int* __restrict__ rowptr, const float* __restrict__ dinv,
                         unsigned* __restrict__ srcw) {
    __shared__ int pos[512];
    __shared__ float dloc[512];
    int t = threadIdx.x;                       // 0..511
    int b = blockIdx.x;
    int base512 = b << BIN_SHIFT;
    int i = base512 + t;
    pos[t]  = (i < N_NODES) ? rowptr[i] : 0;
    dloc[t] = (i < N_NODES) ? dinv[i] : 0.f;
    __syncthreads();
    int n = gcnt[b];
    const unsigned* rec = gbin + (size_t)b * GBIN_CAP;
    for (int j = t; j < n; j += 512) {
        unsigned r = rec[j];
        int s  = (int)(r & 0xFFFFu);
        int dl = (int)(r >> 16) - base512;
        int slot = atomicAdd(&pos[dl], 1);
        float norm = dinv[s] * dloc[dl];
        srcw[slot] = (unsigned)s | (f32_to_h16(norm) << 16);
    }
}

// ---- 5. fused layer-1 aggregate + self-loop + bias + relu + gemm2 for a
//         16-node tile (weighted records; h1r staged in LDS; 4 waves MFMA
//         over 64 padded output columns).
__global__ void k_agg1g2(const int* __restrict__ rowptr, const unsigned* __restrict__ srcw,
                         const float* __restrict__ dinv, const __hip_bfloat16* __restrict__ h1b,
                         const float* __restrict__ b1, const __hip_bfloat16* __restrict__ w2t,
                         __hip_bfloat16* __restrict__ h2b) {
    __shared__ __align__(16) short h1r[16][136];   // +8 bf16 pad
    int t = threadIdx.x, wave = t >> 6, lane = t & 63;
    int node0 = blockIdx.x * 16;
    const unsigned* h1u = (const unsigned*)h1b;
#pragma unroll
    for (int i = 0; i < 4; i++) {
        int row = wave * 4 + i;
        int node = node0 + row;
        float di = dinv[node];
        int beg = __builtin_amdgcn_readfirstlane(rowptr[node]);
        int end = __builtin_amdgcn_readfirstlane(rowptr[node + 1]);
        float2 acc = unpack_bf2(h1u[(size_t)node * 64 + lane]);
        float w0 = di * di;
        acc.x *= w0; acc.y *= w0;
        int e = beg;
        for (; e + 7 < end; e += 8) {
            unsigned p[8];
#pragma unroll
            for (int j = 0; j < 8; j++) p[j] = srcw[e + j];       // uniform -> s_load
            unsigned u[8];
#pragma unroll
            for (int j = 0; j < 8; j++)
                u[j] = h1u[(size_t)(p[j] & 0xFFFFu) * 64 + lane];
#pragma unroll
            for (int j = 0; j < 8; j++) {
                float w = h16_to_f32(p[j] >> 16);
                float2 v = unpack_bf2(u[j]);
                acc.x += v.x * w;
                acc.y += v.y * w;
            }
        }
        for (; e < end; e++) {
            unsigned p = srcw[e];
            float w = h16_to_f32(p >> 16);
            float2 v = unpack_bf2(h1u[(size_t)(p & 0xFFFFu) * 64 + lane]);
            acc.x += v.x * w;
            acc.y += v.y * w;
        }
        float2 bb = ((const float2*)b1)[lane];
        acc.x = fmaxf(acc.x + bb.x, 0.f);
        acc.y = fmaxf(acc.y + bb.y, 0.f);
        ((unsigned*)&h1r[row][0])[lane] = pack_bf2(acc.x, acc.y);
    }
    __syncthreads();
    {
        int m = lane & 15, q = lane >> 4;
        bf16x8 A[4];
#pragma unroll
        for (int kt = 0; kt < 4; kt++)
            A[kt] = *(const bf16x8*)(&h1r[m][q * 8 + kt * 32]);
        int c = wave;
        f32x4 acc = {0.f, 0.f, 0.f, 0.f};
        const __hip_bfloat16* brow = w2t + (size_t)(c * 16 + m) * F_HID + q * 8;
#pragma unroll
        for (int kt = 0; kt < 4; kt++) {
            bf16x8 B = *(const bf16x8*)(brow + kt * 32);
            acc = __builtin_amdgcn_mfma_f32_16x16x32_bf16(A[kt], B, acc, 0, 0, 0);
        }
        int col = c * 16 + m;
#pragma unroll
        for (int r = 0; r < 4; r++)
            h2b[(size_t)(node0 + q * 4 + r) * F_OUT_P + col] = __float2bfloat16(acc[r]);
    }
}

// ---- 6. fused layer-2 aggregate + self-loop + bias + log_softmax.
//         h2b rows are 64 bf16 = one 128B line; all 64 lanes load.
__global__ void k_agg2f(const int* __restrict__ rowptr, const unsigned* __restrict__ srcw,
                        const float* __restrict__ dinv,
                        const unsigned short* __restrict__ h2b,
                        const float* __restrict__ b2, float* __restrict__ out) {
    int wave = threadIdx.x >> 6, lane = threadIdx.x & 63;
    int node = blockIdx.x * 4 + wave;
    float di = dinv[node];
    int beg = __builtin_amdgcn_readfirstlane(rowptr[node]);
    int end = __builtin_amdgcn_readfirstlane(rowptr[node + 1]);
    float acc = bf16u_to_f32(h2b[(size_t)node * F_OUT_P + lane]) * di * di;
    int e = beg;
    for (; e + 7 < end; e += 8) {
        unsigned p[8];
#pragma unroll
        for (int j = 0; j < 8; j++) p[j] = srcw[e + j];          // uniform -> s_load
        float v[8];
#pragma unroll
        for (int j = 0; j < 8; j++)
            v[j] = bf16u_to_f32(h2b[(size_t)(p[j] & 0xFFFFu) * F_OUT_P + lane]);
#pragma unroll
        for (int j = 0; j < 8; j++)
            acc += v[j] * h16_to_f32(p[j] >> 16);
    }
    for (; e < end; e++) {
        unsigned p = srcw[e];
        acc += bf16u_to_f32(h2b[(size_t)(p & 0xFFFFu) * F_OUT_P + lane]) * h16_to_f32(p >> 16);
    }
    float v = (lane < F_OUT) ? acc + b2[lane] : -INFINITY;
    float m = v;
    for (int off = 32; off; off >>= 1) m = fmaxf(m, __shfl_xor(m, off));
    float ex = (lane < F_OUT) ? __expf(v - m) : 0.f;
    float ssum = ex;
    for (int off = 32; off; off >>= 1) ssum += __shfl_xor(ssum, off);
    float ls = __logf(ssum);
    if (lane < F_OUT)
        out[(size_t)node * F_OUT + lane] = v - m - ls;
}

extern "C" void kernel_launch(void* const* d_in, const int* in_sizes, int n_in,
                              void* d_out, int out_size, void* d_ws, size_t ws_size,
                              hipStream_t stream) {
    const float* x  = (const float*)d_in[0];
    const float* W1 = (const float*)d_in[1];
    const float* b1 = (const float*)d_in[2];
    const float* W2 = (const float*)d_in[3];
    const float* b2 = (const float*)d_in[4];
    const unsigned int* ew = (const unsigned int*)d_in[5];
    float* out = (float*)d_out;

    // workspace (~27 MB)
    char* ws = (char*)d_ws;
    int*   flag     = (int*)ws;   ws += 256;
    int*   gcnt     = (int*)ws;   ws += 512;
    float* dinv     = (float*)ws; ws += ((N_NODES * 4 + 255) / 256) * 256;
    int*   rowptr   = (int*)ws;   ws += (((N_NODES + 1) * 4 + 255) / 256) * 256;
    unsigned* gbin  = (unsigned*)ws; ws += (size_t)NBIN * GBIN_CAP * 4;   // 3.6 MB
    unsigned* srcw  = (unsigned*)ws; ws += (size_t)N_EDGES * 4;           // 3.2 MB
    __hip_bfloat16* w1t  = (__hip_bfloat16*)ws; ws += F_IN * F_HID * 2;
    __hip_bfloat16* w2t  = (__hip_bfloat16*)ws; ws += F_OUT_P * F_HID * 2;
    __hip_bfloat16* h1b  = (__hip_bfloat16*)ws; ws += (size_t)N_NODES * F_HID * 2;  // row-major
    __hip_bfloat16* h2b  = (__hip_bfloat16*)ws; ws += (size_t)N_NODES * F_OUT_P * 2; // 6.4 MB

    k_init   <<<CVT_BLOCKS + 1, 256, 0, stream>>>(ew, W1, W2, w1t, w2t, flag, gcnt);
    k_bing1  <<<BIN_BLOCKS + G1_BLOCKS, 256, 0, stream>>>(ew, flag, gcnt, gbin, x, w1t, h1b);
    k_passB1 <<<NBIN, 512, 0, stream>>>(gcnt, gbin, rowptr, dinv);
    k_passB2 <<<NBIN, 512, 0, stream>>>(gcnt, gbin, rowptr, dinv, srcw);
    k_agg1g2 <<<N_NODES / 16, 256, 0, stream>>>(rowptr, srcw, dinv, h1b, b1, w2t, h2b);
    k_agg2f  <<<N_NODES / 4, 256, 0, stream>>>(rowptr, srcw, dinv,
                                               (const unsigned short*)h2b, b2, out);
}